// Round 5
// baseline (449.648 us; speedup 1.0000x reference)
//
#include <hip/hip_runtime.h>
#include <hip/hip_bf16.h>

// FactorizedDenseAttention, MI355X/gfx950.  ALL I/O FP32.
// S[i,j] = sum_m C[i,m]*B[j,m], C = 32*(a[2m]+a[2m+1]) (rank 32)
//   a = q@Wa^T+ba (64ch), B = q@Wb^T+bb (32ch); P = softmax(S); O = P@v.
// S via hi/lo bf16 Dekker split -> 4 MFMAs (16x16x32); stats and P phases
// run bitwise-identical MFMA sequences so exp(S-m)<=1, =1 at the max.
// d_out = [O: H*L*64 f32][P: H*L*L f32].
// R5: stats merged into k_pvs (2 internal passes, no rowM/L roundtrip),
//     XCD-aware head swizzle (2 heads/XCD working set, L2-resident),
//     fp32 P staged in LDS -> dwordx4 NT stores (256B runs),
//     k_cb 4-way m-split (4 waves/SIMD).

#define HN 16
#define LN 2048
#define KR 32

typedef __attribute__((ext_vector_type(8))) short bf16x8;
typedef __attribute__((ext_vector_type(4))) float f32x4;

__device__ __forceinline__ float b2f(unsigned short u) {
    return __uint_as_float(((unsigned int)u) << 16);
}
__device__ __forceinline__ unsigned short f2b(float f) {
    __hip_bfloat16 h = __float2bfloat16(f);   // RNE
    return *reinterpret_cast<unsigned short*>(&h);
}

// ---------------------------------------------------------------------------
// K1a: thread = (row, m-quarter): 8 m's per thread. Weights in LDS.
// ---------------------------------------------------------------------------
__global__ __launch_bounds__(256) void k_cb(
    const float* __restrict__ q,
    const float* __restrict__ Wa, const float* __restrict__ ba,
    const float* __restrict__ Wb, const float* __restrict__ bb,
    unsigned short* __restrict__ Chi, unsigned short* __restrict__ Clo,
    unsigned short* __restrict__ Bhi, unsigned short* __restrict__ Blo)
{
    __shared__ float sWa[64 * 64];
    __shared__ float sWb[32 * 64];
    __shared__ float sba[64];
    __shared__ float sbb[32];
    const int tid = threadIdx.x;
    for (int i = tid; i < 64 * 64; i += 256) sWa[i] = Wa[i];
    for (int i = tid; i < 32 * 64; i += 256) sWb[i] = Wb[i];
    if (tid < 64) sba[tid] = ba[tid];
    if (tid < 32) sbb[tid] = bb[tid];
    __syncthreads();

    const int t = blockIdx.x * 256 + tid;
    const int row = t >> 2, mh = (t & 3) * 8;         // m in [mh, mh+8)
    float qf[64];
    const float4* q4p = reinterpret_cast<const float4*>(q + (size_t)row * 64);
    #pragma unroll
    for (int k4 = 0; k4 < 16; ++k4) {
        float4 u = q4p[k4];
        qf[4*k4+0] = u.x; qf[4*k4+1] = u.y; qf[4*k4+2] = u.z; qf[4*k4+3] = u.w;
    }
    const int ob = row * KR;
    #pragma unroll 1
    for (int mi = 0; mi < 8; ++mi) {
        const int m = mh + mi;
        float a0 = sba[2*m], a1 = sba[2*m+1], bv = sbb[m];
        const float4* wa0 = reinterpret_cast<const float4*>(&sWa[(2*m) * 64]);
        const float4* wa1 = reinterpret_cast<const float4*>(&sWa[(2*m+1) * 64]);
        const float4* wb0 = reinterpret_cast<const float4*>(&sWb[m * 64]);
        #pragma unroll
        for (int k4 = 0; k4 < 16; ++k4) {
            float4 w0 = wa0[k4], w1 = wa1[k4], w2 = wb0[k4];
            float x0 = qf[4*k4], x1 = qf[4*k4+1], x2 = qf[4*k4+2], x3 = qf[4*k4+3];
            a0 = fmaf(x0, w0.x, a0); a0 = fmaf(x1, w0.y, a0);
            a0 = fmaf(x2, w0.z, a0); a0 = fmaf(x3, w0.w, a0);
            a1 = fmaf(x0, w1.x, a1); a1 = fmaf(x1, w1.y, a1);
            a1 = fmaf(x2, w1.z, a1); a1 = fmaf(x3, w1.w, a1);
            bv = fmaf(x0, w2.x, bv); bv = fmaf(x1, w2.y, bv);
            bv = fmaf(x2, w2.z, bv); bv = fmaf(x3, w2.w, bv);
        }
        float c = 32.f * (a0 + a1);                   // fold repeat factor
        unsigned short ch = f2b(c);
        Chi[ob + m] = ch; Clo[ob + m] = f2b(c - b2f(ch));
        unsigned short bh = f2b(bv);
        Bhi[ob + m] = bh; Blo[ob + m] = f2b(bv - b2f(bh));
    }
}

// ---------------------------------------------------------------------------
// K1b: Vt[h][d][j] = bf16(v[h][j][d])
// ---------------------------------------------------------------------------
__global__ __launch_bounds__(256) void k_vt(
    const float* __restrict__ v, unsigned short* __restrict__ Vt)
{
    __shared__ unsigned short sv[64 * 66];
    const int tid = threadIdx.x;
    const int h = blockIdx.x >> 5, jt = blockIdx.x & 31;
    const float* src = v + (size_t)(h * LN + jt * 64) * 64;
    for (int i = tid; i < 4096; i += 256)
        sv[(i >> 6) * 66 + (i & 63)] = f2b(src[i]);
    __syncthreads();
    for (int i = tid; i < 4096; i += 256) {
        int d = i >> 6, j = i & 63;
        Vt[(size_t)(h * 64 + d) * LN + jt * 64 + j] = sv[j * 66 + d];
    }
}

// ---------------------------------------------------------------------------
// K2 (merged): phase A = row stats (m, 1/l) over all 32 chunks; phase B =
// recompute S (identical MFMA sequence), P = exp(S-m)/l, fp32 P staged in
// wave-private LDS -> dwordx4 NT stores; bf16 P staged for PV A-operand.
// Head mapping is XCD-swizzled: h = (b%8)*2 + (b>>8)  => 2 heads per XCD.
// ---------------------------------------------------------------------------
__global__ __launch_bounds__(256) void k_pvs(
    const unsigned short* __restrict__ Chi, const unsigned short* __restrict__ Clo,
    const unsigned short* __restrict__ Bhi, const unsigned short* __restrict__ Blo,
    const unsigned short* __restrict__ Vt,
    float* __restrict__ outO, float* __restrict__ outP)
{
    __shared__ unsigned short Ps[4][16 * 68];   // bf16 P, per wave, stride 68
    __shared__ float Psf[4][16 * 68];           // fp32 P, per wave, stride 68
    const int b = blockIdx.x;
    const int h = (b & 7) * 2 + (b >> 8);       // XCD-aware head mapping
    const int tile = (b >> 3) & 31;
    const int tid = threadIdx.x, w = tid >> 6, lane = tid & 63;
    const int quad = lane >> 4, n16 = lane & 15;
    const int rbase = tile * 64 + w * 16;
    const int hL = h * LN;
    unsigned short* ps = &Ps[w][0];
    float* psf = &Psf[w][0];

    const bf16x8 ahi = *reinterpret_cast<const bf16x8*>(Chi + (size_t)(hL + rbase + n16) * KR + quad * 8);
    const bf16x8 alo = *reinterpret_cast<const bf16x8*>(Clo + (size_t)(hL + rbase + n16) * KR + quad * 8);

    const unsigned short* bhiP = Bhi + (size_t)(hL + n16) * KR + quad * 8;
    const unsigned short* bloP = Blo + (size_t)(hL + n16) * KR + quad * 8;

    const unsigned short* vrow[4];
    #pragma unroll
    for (int di = 0; di < 4; ++di)
        vrow[di] = Vt + (size_t)(h * 64 + di * 16 + n16) * LN + quad * 8;

    f32x4 zero = {0.f, 0.f, 0.f, 0.f};

    // ---- phase A: stats ----
    float m0[4] = {-1e30f, -1e30f, -1e30f, -1e30f};
    float l0[4] = {0.f, 0.f, 0.f, 0.f};
    for (int jc = 0; jc < 32; ++jc) {
        const int jb = jc * 64;
        f32x4 s[4];
        #pragma unroll
        for (int ni = 0; ni < 4; ++ni) {
            const int off = (jb + ni * 16) * KR;
            bf16x8 bhi = *reinterpret_cast<const bf16x8*>(bhiP + off);
            bf16x8 blo = *reinterpret_cast<const bf16x8*>(bloP + off);
            f32x4 acc = zero;
            acc = __builtin_amdgcn_mfma_f32_16x16x32_bf16(ahi, bhi, acc, 0, 0, 0);
            acc = __builtin_amdgcn_mfma_f32_16x16x32_bf16(ahi, blo, acc, 0, 0, 0);
            acc = __builtin_amdgcn_mfma_f32_16x16x32_bf16(alo, bhi, acc, 0, 0, 0);
            acc = __builtin_amdgcn_mfma_f32_16x16x32_bf16(alo, blo, acc, 0, 0, 0);
            s[ni] = acc;
        }
        #pragma unroll
        for (int r = 0; r < 4; ++r) {
            float v0 = s[0][r], v1 = s[1][r], v2 = s[2][r], v3 = s[3][r];
            float mx = fmaxf(fmaxf(v0, v1), fmaxf(v2, v3));
            float mn = fmaxf(m0[r], mx);
            l0[r] = l0[r] * __expf(m0[r] - mn)
                  + __expf(v0 - mn) + __expf(v1 - mn)
                  + __expf(v2 - mn) + __expf(v3 - mn);
            m0[r] = mn;
        }
    }
    #pragma unroll
    for (int off = 1; off <= 8; off <<= 1) {        // butterfly: all 16 lanes
        #pragma unroll
        for (int r = 0; r < 4; ++r) {
            float m2 = __shfl_xor(m0[r], off, 64);
            float l2 = __shfl_xor(l0[r], off, 64);
            float mn = fmaxf(m0[r], m2);
            l0[r] = l0[r] * __expf(m0[r] - mn) + l2 * __expf(m2 - mn);
            m0[r] = mn;
        }
    }
    float mr[4], li[4];
    #pragma unroll
    for (int r = 0; r < 4; ++r) { mr[r] = m0[r]; li[r] = 1.f / l0[r]; }

    // ---- phase B: P + PV ----
    f32x4 o[4];
    #pragma unroll
    for (int di = 0; di < 4; ++di) o[di] = zero;

    for (int jc = 0; jc < 32; ++jc) {
        const int jb = jc * 64;
        #pragma unroll
        for (int ni = 0; ni < 4; ++ni) {
            const int off = (jb + ni * 16) * KR;
            bf16x8 bhi = *reinterpret_cast<const bf16x8*>(bhiP + off);
            bf16x8 blo = *reinterpret_cast<const bf16x8*>(bloP + off);
            f32x4 acc = zero;
            acc = __builtin_amdgcn_mfma_f32_16x16x32_bf16(ahi, bhi, acc, 0, 0, 0);
            acc = __builtin_amdgcn_mfma_f32_16x16x32_bf16(ahi, blo, acc, 0, 0, 0);
            acc = __builtin_amdgcn_mfma_f32_16x16x32_bf16(alo, bhi, acc, 0, 0, 0);
            acc = __builtin_amdgcn_mfma_f32_16x16x32_bf16(alo, blo, acc, 0, 0, 0);
            #pragma unroll
            for (int r = 0; r < 4; ++r) {
                float p = __expf(acc[r] - mr[r]) * li[r];
                const int sidx = (quad * 4 + r) * 68 + ni * 16 + n16;
                psf[sidx] = p;
                ps[sidx] = f2b(p);
            }
        }
        // vectorized NT store of fp32 P: 4 rows x 256B contiguous per instr
        #pragma unroll
        for (int rr = 0; rr < 4; ++rr) {
            const int prow = rr * 4 + quad;
            const int pcol = n16 * 4;
            f32x4 val = *reinterpret_cast<f32x4*>(psf + prow * 68 + pcol);
            __builtin_nontemporal_store(val,
                reinterpret_cast<f32x4*>(outP + (size_t)(hL + rbase + prow) * LN + jb + pcol));
        }
        // PV: O += P(chunk) @ V(chunk); in-wave LDS hazards ordered by lgkmcnt
        #pragma unroll
        for (int ks = 0; ks < 2; ++ks) {
            const bf16x8 pa = *reinterpret_cast<const bf16x8*>(ps + n16 * 68 + ks * 32 + quad * 8);
            #pragma unroll
            for (int di = 0; di < 4; ++di) {
                const bf16x8 vb = *reinterpret_cast<const bf16x8*>(vrow[di] + jb + ks * 32);
                o[di] = __builtin_amdgcn_mfma_f32_16x16x32_bf16(pa, vb, o[di], 0, 0, 0);
            }
        }
    }
    #pragma unroll
    for (int di = 0; di < 4; ++di) {
        #pragma unroll
        for (int r = 0; r < 4; ++r) {
            const int grow = rbase + quad * 4 + r;
            __builtin_nontemporal_store(o[di][r],
                &outO[(size_t)(hL + grow) * 64 + di * 16 + n16]);
        }
    }
}

// ---------------------------------------------------------------------------
extern "C" void kernel_launch(void* const* d_in, const int* in_sizes, int n_in,
                              void* d_out, int out_size, void* d_ws, size_t ws_size,
                              hipStream_t stream)
{
    (void)in_sizes; (void)n_in; (void)out_size; (void)ws_size;
    const float* q  = (const float*)d_in[0];
    const float* v  = (const float*)d_in[1];
    const float* Wa = (const float*)d_in[2];
    const float* ba = (const float*)d_in[3];
    const float* Wb = (const float*)d_in[4];
    const float* bb = (const float*)d_in[5];

    float* out = (float*)d_out;
    char* wsb = (char*)d_ws;
    const size_t CBb = (size_t)HN * LN * KR * 2;   // 2MB per bf16 plane
    unsigned short* Chi = (unsigned short*)(wsb + 0 * CBb);
    unsigned short* Clo = (unsigned short*)(wsb + 1 * CBb);
    unsigned short* Bhi = (unsigned short*)(wsb + 2 * CBb);
    unsigned short* Blo = (unsigned short*)(wsb + 3 * CBb);
    unsigned short* Vt  = (unsigned short*)(wsb + 4 * CBb);     // 4MB

    float* outO = out;                          // [H*L*64]
    float* outP = out + (size_t)HN * LN * 64;   // [H*L*L]

    hipLaunchKernelGGL(k_cb, dim3(512), dim3(256), 0, stream,
                       q, Wa, ba, Wb, bb, Chi, Clo, Bhi, Blo);
    hipLaunchKernelGGL(k_vt, dim3(512), dim3(256), 0, stream, v, Vt);
    hipLaunchKernelGGL(k_pvs, dim3(512), dim3(256), 0, stream,
                       Chi, Clo, Bhi, Blo, Vt, outO, outP);
}

// Round 6
// 389.383 us; speedup vs baseline: 1.1548x; 1.1548x over previous
//
#include <hip/hip_runtime.h>
#include <hip/hip_bf16.h>

// FactorizedDenseAttention, MI355X/gfx950.  ALL I/O FP32.
// S[i,j] = sum_m C[i,m]*B[j,m], C = 32*(a[2m]+a[2m+1]) (rank 32)
//   a = q@Wa^T+ba (64ch), B = q@Wb^T+bb (32ch); P = softmax(S); O = P@v.
// S via hi/lo bf16 Dekker split -> 4 MFMAs (16x16x32); stats and P phases
// run bitwise-identical MFMA sequences so exp(S-m)<=1, =1 at the max.
// d_out = [O: H*L*64 f32][P: H*L*L f32].
// R6: LDS chunk-tile staging via global_load_lds width=16 shared by all 4
// waves (L2 read traffic /4: was 192MB/XCD, R5 evidence: latency-bound at
// 2 waves/SIMD vs L2). Tile layout k-granule-outer for DMA contiguity +
// 2-way-only LDS bank aliasing. Numerics identical to R5 (absmax 0.03125).

#define HN 16
#define LN 2048
#define KR 32

typedef __attribute__((ext_vector_type(8))) short bf16x8;
typedef __attribute__((ext_vector_type(4))) float f32x4;

__device__ __forceinline__ float b2f(unsigned short u) {
    return __uint_as_float(((unsigned int)u) << 16);
}
__device__ __forceinline__ unsigned short f2b(float f) {
    __hip_bfloat16 h = __float2bfloat16(f);   // RNE
    return *reinterpret_cast<unsigned short*>(&h);
}
__device__ __forceinline__ void glds16(const void* g, void* l) {
    __builtin_amdgcn_global_load_lds(
        (const __attribute__((address_space(1))) unsigned int*)g,
        (__attribute__((address_space(3))) unsigned int*)l, 16, 0, 0);
}

// Tile workspace layout, per (h, jc): 16KB = 8192 shorts:
//   [0,    2048): Bhi tile  [kg=0..3][c=0..63] granules of 8 bf16 (k=kg*8..+8)
//   [2048, 4096): Blo tile  same layout
//   [4096, 8192): Vt  tile  [jg=0..7][d=0..63] granules of 8 bf16 (j=jb+jg*8..+8)
#define TILE_SH 8192

// ---------------------------------------------------------------------------
// K1a: thread = (row, kg): 8 m's per thread. Weights in LDS.
// Writes Chi/Clo row-major (A-frags) and Bhi/Blo in tile layout (staging).
// ---------------------------------------------------------------------------
__global__ __launch_bounds__(256) void k_cb(
    const float* __restrict__ q,
    const float* __restrict__ Wa, const float* __restrict__ ba,
    const float* __restrict__ Wb, const float* __restrict__ bb,
    unsigned short* __restrict__ Chi, unsigned short* __restrict__ Clo,
    unsigned short* __restrict__ Tile)
{
    __shared__ float sWa[64 * 64];
    __shared__ float sWb[32 * 64];
    __shared__ float sba[64];
    __shared__ float sbb[32];
    const int tid = threadIdx.x;
    for (int i = tid; i < 64 * 64; i += 256) sWa[i] = Wa[i];
    for (int i = tid; i < 32 * 64; i += 256) sWb[i] = Wb[i];
    if (tid < 64) sba[tid] = ba[tid];
    if (tid < 32) sbb[tid] = bb[tid];
    __syncthreads();

    const int t = blockIdx.x * 256 + tid;
    const int row = t >> 2, kg = t & 3, mh = kg * 8;   // m in [mh, mh+8)
    const int h = row >> 11, i = row & 2047;
    const int jc = i >> 6, c = i & 63;

    float qf[64];
    const float4* q4p = reinterpret_cast<const float4*>(q + (size_t)row * 64);
    #pragma unroll
    for (int k4 = 0; k4 < 16; ++k4) {
        float4 u = q4p[k4];
        qf[4*k4+0] = u.x; qf[4*k4+1] = u.y; qf[4*k4+2] = u.z; qf[4*k4+3] = u.w;
    }
    unsigned short chb[8], clb[8], bhb[8], blb[8];
    #pragma unroll
    for (int mi = 0; mi < 8; ++mi) {
        const int m = mh + mi;
        float a0 = sba[2*m], a1 = sba[2*m+1], bv = sbb[m];
        const float4* wa0 = reinterpret_cast<const float4*>(&sWa[(2*m) * 64]);
        const float4* wa1 = reinterpret_cast<const float4*>(&sWa[(2*m+1) * 64]);
        const float4* wb0 = reinterpret_cast<const float4*>(&sWb[m * 64]);
        #pragma unroll
        for (int k4 = 0; k4 < 16; ++k4) {
            float4 w0 = wa0[k4], w1 = wa1[k4], w2 = wb0[k4];
            float x0 = qf[4*k4], x1 = qf[4*k4+1], x2 = qf[4*k4+2], x3 = qf[4*k4+3];
            a0 = fmaf(x0, w0.x, a0); a0 = fmaf(x1, w0.y, a0);
            a0 = fmaf(x2, w0.z, a0); a0 = fmaf(x3, w0.w, a0);
            a1 = fmaf(x0, w1.x, a1); a1 = fmaf(x1, w1.y, a1);
            a1 = fmaf(x2, w1.z, a1); a1 = fmaf(x3, w1.w, a1);
            bv = fmaf(x0, w2.x, bv); bv = fmaf(x1, w2.y, bv);
            bv = fmaf(x2, w2.z, bv); bv = fmaf(x3, w2.w, bv);
        }
        float cc = 32.f * (a0 + a1);                  // fold repeat factor
        unsigned short ch = f2b(cc);
        chb[mi] = ch; clb[mi] = f2b(cc - b2f(ch));
        unsigned short bh = f2b(bv);
        bhb[mi] = bh; blb[mi] = f2b(bv - b2f(bh));
    }
    // A-operand planes, row-major [row][m]
    *reinterpret_cast<uint4*>(Chi + (size_t)row * KR + mh) = *reinterpret_cast<uint4*>(chb);
    *reinterpret_cast<uint4*>(Clo + (size_t)row * KR + mh) = *reinterpret_cast<uint4*>(clb);
    // B-operand tiles, [h][jc]: granule (kg, c)
    unsigned short* tb = Tile + (size_t)(h * 32 + jc) * TILE_SH + (kg * 64 + c) * 8;
    *reinterpret_cast<uint4*>(tb)        = *reinterpret_cast<uint4*>(bhb);
    *reinterpret_cast<uint4*>(tb + 2048) = *reinterpret_cast<uint4*>(blb);
}

// ---------------------------------------------------------------------------
// K1b: V tiles: Tile[h][jc] Vt region [jg][d] granules, granule (jg,d) =
// bf16(v[h][jb+jg*8 .. +8][d]).
// ---------------------------------------------------------------------------
__global__ __launch_bounds__(256) void k_vtc(
    const float* __restrict__ v, unsigned short* __restrict__ Tile)
{
    __shared__ unsigned short sv[64 * 66];   // [j][d], stride 66
    const int tid = threadIdx.x;
    const int h = blockIdx.x >> 5, jc = blockIdx.x & 31;
    const float* src = v + (size_t)(h * LN + jc * 64) * 64;
    for (int i = tid; i < 4096; i += 256)
        sv[(i >> 6) * 66 + (i & 63)] = f2b(src[i]);
    __syncthreads();
    unsigned short* vt = Tile + (size_t)(h * 32 + jc) * TILE_SH + 4096;
    #pragma unroll
    for (int it = 0; it < 2; ++it) {
        const int gi = tid + it * 256;               // 0..511
        const int jg = gi >> 6, d = gi & 63;
        unsigned short g8[8];
        #pragma unroll
        for (int cjj = 0; cjj < 8; ++cjj)
            g8[cjj] = sv[(jg * 8 + cjj) * 66 + d];
        *reinterpret_cast<uint4*>(vt + (jg * 64 + d) * 8) = *reinterpret_cast<uint4*>(g8);
    }
}

// ---------------------------------------------------------------------------
// K2: stats + P + PV, chunk tiles staged in LDS via global_load_lds and
// shared by the block's 4 waves. h = (b%8)*2 + (b>>8): 2 heads per XCD.
// ---------------------------------------------------------------------------
__global__ __launch_bounds__(256) void k_pvs(
    const unsigned short* __restrict__ Chi, const unsigned short* __restrict__ Clo,
    const unsigned short* __restrict__ Tile,
    float* __restrict__ outO, float* __restrict__ outP)
{
    __shared__ unsigned short sT[TILE_SH];      // 16KB staged chunk tile
    __shared__ unsigned short Ps[4][16 * 68];   // bf16 P, per wave
    __shared__ float Psf[4][16 * 68];           // fp32 P, per wave
    const int b = blockIdx.x;
    const int h = (b & 7) * 2 + (b >> 8);       // XCD-aware head mapping
    const int tile = (b >> 3) & 31;
    const int tid = threadIdx.x, w = tid >> 6, lane = tid & 63;
    const int quad = lane >> 4, n16 = lane & 15;
    const int rbase = tile * 64 + w * 16;
    const int hL = h * LN;
    unsigned short* ps = &Ps[w][0];
    float* psf = &Psf[w][0];

    const bf16x8 ahi = *reinterpret_cast<const bf16x8*>(Chi + (size_t)(hL + rbase + n16) * KR + quad * 8);
    const bf16x8 alo = *reinterpret_cast<const bf16x8*>(Clo + (size_t)(hL + rbase + n16) * KR + quad * 8);

    const char* tBase = (const char*)(Tile + (size_t)(h * 32) * TILE_SH);
    char* sTb = (char*)sT;
    const int fragB = (quad * 64 + n16) * 8;    // + ni*128 shorts
    const int lane16 = lane * 16;

    f32x4 zero = {0.f, 0.f, 0.f, 0.f};

    // ---- phase A: stats ----
    float m0[4] = {-1e30f, -1e30f, -1e30f, -1e30f};
    float l0[4] = {0.f, 0.f, 0.f, 0.f};
    for (int jc = 0; jc < 32; ++jc) {
        const char* g = tBase + (size_t)jc * (TILE_SH * 2);
        glds16(g + w * 1024 + lane16,      sTb + w * 1024);          // B planes:
        glds16(g + (w + 4) * 1024 + lane16, sTb + (w + 4) * 1024);   // 8KB
        __syncthreads();
        f32x4 s[4];
        #pragma unroll
        for (int ni = 0; ni < 4; ++ni) {
            bf16x8 bhi = *reinterpret_cast<const bf16x8*>(sT + fragB + ni * 128);
            bf16x8 blo = *reinterpret_cast<const bf16x8*>(sT + 2048 + fragB + ni * 128);
            f32x4 acc = zero;
            acc = __builtin_amdgcn_mfma_f32_16x16x32_bf16(ahi, bhi, acc, 0, 0, 0);
            acc = __builtin_amdgcn_mfma_f32_16x16x32_bf16(ahi, blo, acc, 0, 0, 0);
            acc = __builtin_amdgcn_mfma_f32_16x16x32_bf16(alo, bhi, acc, 0, 0, 0);
            acc = __builtin_amdgcn_mfma_f32_16x16x32_bf16(alo, blo, acc, 0, 0, 0);
            s[ni] = acc;
        }
        #pragma unroll
        for (int r = 0; r < 4; ++r) {
            float v0 = s[0][r], v1 = s[1][r], v2 = s[2][r], v3 = s[3][r];
            float mx = fmaxf(fmaxf(v0, v1), fmaxf(v2, v3));
            float mn = fmaxf(m0[r], mx);
            l0[r] = l0[r] * __expf(m0[r] - mn)
                  + __expf(v0 - mn) + __expf(v1 - mn)
                  + __expf(v2 - mn) + __expf(v3 - mn);
            m0[r] = mn;
        }
        __syncthreads();   // WAR: next chunk's DMA overwrites sT
    }
    #pragma unroll
    for (int off = 1; off <= 8; off <<= 1) {        // butterfly: all 16 lanes
        #pragma unroll
        for (int r = 0; r < 4; ++r) {
            float m2 = __shfl_xor(m0[r], off, 64);
            float l2 = __shfl_xor(l0[r], off, 64);
            float mn = fmaxf(m0[r], m2);
            l0[r] = l0[r] * __expf(m0[r] - mn) + l2 * __expf(m2 - mn);
            m0[r] = mn;
        }
    }
    float mr[4], li[4];
    #pragma unroll
    for (int r = 0; r < 4; ++r) { mr[r] = m0[r]; li[r] = 1.f / l0[r]; }

    // ---- phase B: P + PV ----
    f32x4 o[4];
    #pragma unroll
    for (int di = 0; di < 4; ++di) o[di] = zero;

    for (int jc = 0; jc < 32; ++jc) {
        const int jb = jc * 64;
        const char* g = tBase + (size_t)jc * (TILE_SH * 2);
        glds16(g + w * 1024 + lane16,        sTb + w * 1024);        // full 16KB
        glds16(g + (w + 4) * 1024 + lane16,  sTb + (w + 4) * 1024);
        glds16(g + (w + 8) * 1024 + lane16,  sTb + (w + 8) * 1024);
        glds16(g + (w + 12) * 1024 + lane16, sTb + (w + 12) * 1024);
        __syncthreads();
        #pragma unroll
        for (int ni = 0; ni < 4; ++ni) {
            bf16x8 bhi = *reinterpret_cast<const bf16x8*>(sT + fragB + ni * 128);
            bf16x8 blo = *reinterpret_cast<const bf16x8*>(sT + 2048 + fragB + ni * 128);
            f32x4 acc = zero;
            acc = __builtin_amdgcn_mfma_f32_16x16x32_bf16(ahi, bhi, acc, 0, 0, 0);
            acc = __builtin_amdgcn_mfma_f32_16x16x32_bf16(ahi, blo, acc, 0, 0, 0);
            acc = __builtin_amdgcn_mfma_f32_16x16x32_bf16(alo, bhi, acc, 0, 0, 0);
            acc = __builtin_amdgcn_mfma_f32_16x16x32_bf16(alo, blo, acc, 0, 0, 0);
            #pragma unroll
            for (int r = 0; r < 4; ++r) {
                float p = __expf(acc[r] - mr[r]) * li[r];
                const int sidx = (quad * 4 + r) * 68 + ni * 16 + n16;
                psf[sidx] = p;
                ps[sidx] = f2b(p);
            }
        }
        // vectorized NT store of fp32 P: 4 rows x 256B contiguous per instr
        #pragma unroll
        for (int rr = 0; rr < 4; ++rr) {
            const int prow = rr * 4 + quad;
            const int pcol = n16 * 4;
            f32x4 val = *reinterpret_cast<f32x4*>(psf + prow * 68 + pcol);
            __builtin_nontemporal_store(val,
                reinterpret_cast<f32x4*>(outP + (size_t)(hL + rbase + prow) * LN + jb + pcol));
        }
        // PV: O += P(chunk) @ V(chunk); in-wave LDS hazards ordered by lgkmcnt
        #pragma unroll
        for (int ks = 0; ks < 2; ++ks) {
            const bf16x8 pa = *reinterpret_cast<const bf16x8*>(ps + n16 * 68 + ks * 32 + quad * 8);
            #pragma unroll
            for (int di = 0; di < 4; ++di) {
                const bf16x8 vb = *reinterpret_cast<const bf16x8*>(
                    sT + 4096 + ((ks * 4 + quad) * 64 + di * 16 + n16) * 8);
                o[di] = __builtin_amdgcn_mfma_f32_16x16x32_bf16(pa, vb, o[di], 0, 0, 0);
            }
        }
        __syncthreads();   // WAR: next chunk's DMA overwrites sT
    }
    #pragma unroll
    for (int di = 0; di < 4; ++di) {
        #pragma unroll
        for (int r = 0; r < 4; ++r) {
            const int grow = rbase + quad * 4 + r;
            __builtin_nontemporal_store(o[di][r],
                &outO[(size_t)(hL + grow) * 64 + di * 16 + n16]);
        }
    }
}

// ---------------------------------------------------------------------------
extern "C" void kernel_launch(void* const* d_in, const int* in_sizes, int n_in,
                              void* d_out, int out_size, void* d_ws, size_t ws_size,
                              hipStream_t stream)
{
    (void)in_sizes; (void)n_in; (void)out_size; (void)ws_size;
    const float* q  = (const float*)d_in[0];
    const float* v  = (const float*)d_in[1];
    const float* Wa = (const float*)d_in[2];
    const float* ba = (const float*)d_in[3];
    const float* Wb = (const float*)d_in[4];
    const float* bb = (const float*)d_in[5];

    float* out = (float*)d_out;
    char* wsb = (char*)d_ws;
    const size_t CBb = (size_t)HN * LN * KR * 2;   // 2MB per bf16 plane
    unsigned short* Chi  = (unsigned short*)(wsb + 0 * CBb);
    unsigned short* Clo  = (unsigned short*)(wsb + 1 * CBb);
    unsigned short* Tile = (unsigned short*)(wsb + 2 * CBb);   // 16 KB x 512 = 8MB

    float* outO = out;                          // [H*L*64]
    float* outP = out + (size_t)HN * LN * 64;   // [H*L*L]

    hipLaunchKernelGGL(k_cb, dim3(512), dim3(256), 0, stream,
                       q, Wa, ba, Wb, bb, Chi, Clo, Tile);
    hipLaunchKernelGGL(k_vtc, dim3(512), dim3(256), 0, stream, v, Tile);
    hipLaunchKernelGGL(k_pvs, dim3(512), dim3(256), 0, stream,
                       Chi, Clo, Tile, outO, outP);
}

// Round 7
// 389.284 us; speedup vs baseline: 1.1551x; 1.0003x over previous
//
#include <hip/hip_runtime.h>
#include <hip/hip_bf16.h>

// FactorizedDenseAttention, MI355X/gfx950.  ALL I/O FP32.
// S[i,j] = sum_m C[i,m]*B[j,m], C = 32*(a[2m]+a[2m+1]) (rank 32)
//   a = q@Wa^T+ba (64ch), B = q@Wb^T+bb (32ch); P = softmax(S); O = P@v.
// S via hi/lo bf16 Dekker split -> 4 MFMAs (16x16x32); stats and P phases
// run bitwise-identical MFMA sequences so exp(S-m)<=1, =1 at the max.
// d_out = [O: H*L*64 f32][P: H*L*L f32].
// R7: double-buffered LDS tile + prefetch (1 barrier/chunk instead of 2;
// DMA for chunk jc+1 overlaps compute on jc; R6 evidence: k_pvs ~120us was
// exposed-DMA-latency-bound, MFMA/VALU/HBM all <25%).

#define HN 16
#define LN 2048
#define KR 32

typedef __attribute__((ext_vector_type(8))) short bf16x8;
typedef __attribute__((ext_vector_type(4))) float f32x4;

__device__ __forceinline__ float b2f(unsigned short u) {
    return __uint_as_float(((unsigned int)u) << 16);
}
__device__ __forceinline__ unsigned short f2b(float f) {
    __hip_bfloat16 h = __float2bfloat16(f);   // RNE
    return *reinterpret_cast<unsigned short*>(&h);
}
__device__ __forceinline__ void glds16(const void* g, void* l) {
    __builtin_amdgcn_global_load_lds(
        (const __attribute__((address_space(1))) unsigned int*)g,
        (__attribute__((address_space(3))) unsigned int*)l, 16, 0, 0);
}

// Tile workspace layout, per (h, jc): 16KB = 8192 shorts:
//   [0,    2048): Bhi tile  [kg=0..3][c=0..63] granules of 8 bf16 (k=kg*8..+8)
//   [2048, 4096): Blo tile  same layout
//   [4096, 8192): Vt  tile  [jg=0..7][d=0..63] granules of 8 bf16 (j=jb+jg*8..+8)
#define TILE_SH 8192

// ---------------------------------------------------------------------------
// K1a: thread = (row, kg): 8 m's per thread. Weights in LDS.
// Writes Chi/Clo row-major (A-frags) and Bhi/Blo in tile layout (staging).
// ---------------------------------------------------------------------------
__global__ __launch_bounds__(256) void k_cb(
    const float* __restrict__ q,
    const float* __restrict__ Wa, const float* __restrict__ ba,
    const float* __restrict__ Wb, const float* __restrict__ bb,
    unsigned short* __restrict__ Chi, unsigned short* __restrict__ Clo,
    unsigned short* __restrict__ Tile)
{
    __shared__ float sWa[64 * 64];
    __shared__ float sWb[32 * 64];
    __shared__ float sba[64];
    __shared__ float sbb[32];
    const int tid = threadIdx.x;
    for (int i = tid; i < 64 * 64; i += 256) sWa[i] = Wa[i];
    for (int i = tid; i < 32 * 64; i += 256) sWb[i] = Wb[i];
    if (tid < 64) sba[tid] = ba[tid];
    if (tid < 32) sbb[tid] = bb[tid];
    __syncthreads();

    const int t = blockIdx.x * 256 + tid;
    const int row = t >> 2, kg = t & 3, mh = kg * 8;   // m in [mh, mh+8)
    const int h = row >> 11, i = row & 2047;
    const int jc = i >> 6, c = i & 63;

    float qf[64];
    const float4* q4p = reinterpret_cast<const float4*>(q + (size_t)row * 64);
    #pragma unroll
    for (int k4 = 0; k4 < 16; ++k4) {
        float4 u = q4p[k4];
        qf[4*k4+0] = u.x; qf[4*k4+1] = u.y; qf[4*k4+2] = u.z; qf[4*k4+3] = u.w;
    }
    unsigned short chb[8], clb[8], bhb[8], blb[8];
    #pragma unroll
    for (int mi = 0; mi < 8; ++mi) {
        const int m = mh + mi;
        float a0 = sba[2*m], a1 = sba[2*m+1], bv = sbb[m];
        const float4* wa0 = reinterpret_cast<const float4*>(&sWa[(2*m) * 64]);
        const float4* wa1 = reinterpret_cast<const float4*>(&sWa[(2*m+1) * 64]);
        const float4* wb0 = reinterpret_cast<const float4*>(&sWb[m * 64]);
        #pragma unroll
        for (int k4 = 0; k4 < 16; ++k4) {
            float4 w0 = wa0[k4], w1 = wa1[k4], w2 = wb0[k4];
            float x0 = qf[4*k4], x1 = qf[4*k4+1], x2 = qf[4*k4+2], x3 = qf[4*k4+3];
            a0 = fmaf(x0, w0.x, a0); a0 = fmaf(x1, w0.y, a0);
            a0 = fmaf(x2, w0.z, a0); a0 = fmaf(x3, w0.w, a0);
            a1 = fmaf(x0, w1.x, a1); a1 = fmaf(x1, w1.y, a1);
            a1 = fmaf(x2, w1.z, a1); a1 = fmaf(x3, w1.w, a1);
            bv = fmaf(x0, w2.x, bv); bv = fmaf(x1, w2.y, bv);
            bv = fmaf(x2, w2.z, bv); bv = fmaf(x3, w2.w, bv);
        }
        float cc = 32.f * (a0 + a1);                  // fold repeat factor
        unsigned short ch = f2b(cc);
        chb[mi] = ch; clb[mi] = f2b(cc - b2f(ch));
        unsigned short bh = f2b(bv);
        bhb[mi] = bh; blb[mi] = f2b(bv - b2f(bh));
    }
    // A-operand planes, row-major [row][m]
    *reinterpret_cast<uint4*>(Chi + (size_t)row * KR + mh) = *reinterpret_cast<uint4*>(chb);
    *reinterpret_cast<uint4*>(Clo + (size_t)row * KR + mh) = *reinterpret_cast<uint4*>(clb);
    // B-operand tiles, [h][jc]: granule (kg, c)
    unsigned short* tb = Tile + (size_t)(h * 32 + jc) * TILE_SH + (kg * 64 + c) * 8;
    *reinterpret_cast<uint4*>(tb)        = *reinterpret_cast<uint4*>(bhb);
    *reinterpret_cast<uint4*>(tb + 2048) = *reinterpret_cast<uint4*>(blb);
}

// ---------------------------------------------------------------------------
// K1b: V tiles: Tile[h][jc] Vt region [jg][d] granules, granule (jg,d) =
// bf16(v[h][jb+jg*8 .. +8][d]).
// ---------------------------------------------------------------------------
__global__ __launch_bounds__(256) void k_vtc(
    const float* __restrict__ v, unsigned short* __restrict__ Tile)
{
    __shared__ unsigned short sv[64 * 66];   // [j][d], stride 66
    const int tid = threadIdx.x;
    const int h = blockIdx.x >> 5, jc = blockIdx.x & 31;
    const float* src = v + (size_t)(h * LN + jc * 64) * 64;
    for (int i = tid; i < 4096; i += 256)
        sv[(i >> 6) * 66 + (i & 63)] = f2b(src[i]);
    __syncthreads();
    unsigned short* vt = Tile + (size_t)(h * 32 + jc) * TILE_SH + 4096;
    #pragma unroll
    for (int it = 0; it < 2; ++it) {
        const int gi = tid + it * 256;               // 0..511
        const int jg = gi >> 6, d = gi & 63;
        unsigned short g8[8];
        #pragma unroll
        for (int cjj = 0; cjj < 8; ++cjj)
            g8[cjj] = sv[(jg * 8 + cjj) * 66 + d];
        *reinterpret_cast<uint4*>(vt + (jg * 64 + d) * 8) = *reinterpret_cast<uint4*>(g8);
    }
}

// ---------------------------------------------------------------------------
// K2: stats + P + PV. Chunk tiles double-buffered in LDS via global_load_lds:
// barrier drains DMA(cur), then prefetch(next) is issued and overlaps the
// whole compute(cur) phase. One barrier per chunk. vmcnt is per-wave: each
// wave drains its own slices before s_barrier; after the barrier all slices
// are visible. h = (b%8)*2 + (b>>8): 2 heads per XCD.
// ---------------------------------------------------------------------------
__global__ __launch_bounds__(256) void k_pvs(
    const unsigned short* __restrict__ Chi, const unsigned short* __restrict__ Clo,
    const unsigned short* __restrict__ Tile,
    float* __restrict__ outO, float* __restrict__ outP)
{
    __shared__ unsigned short sT[2][TILE_SH];   // 2 x 16KB chunk tiles
    __shared__ unsigned short Ps[4][16 * 68];   // bf16 P, per wave
    __shared__ float Psf[4][16 * 68];           // fp32 P, per wave
    const int b = blockIdx.x;
    const int h = (b & 7) * 2 + (b >> 8);       // XCD-aware head mapping
    const int tile = (b >> 3) & 31;
    const int tid = threadIdx.x, w = tid >> 6, lane = tid & 63;
    const int quad = lane >> 4, n16 = lane & 15;
    const int rbase = tile * 64 + w * 16;
    const int hL = h * LN;
    unsigned short* ps = &Ps[w][0];
    float* psf = &Psf[w][0];

    const bf16x8 ahi = *reinterpret_cast<const bf16x8*>(Chi + (size_t)(hL + rbase + n16) * KR + quad * 8);
    const bf16x8 alo = *reinterpret_cast<const bf16x8*>(Clo + (size_t)(hL + rbase + n16) * KR + quad * 8);

    const char* tBase = (const char*)(Tile + (size_t)(h * 32) * TILE_SH);
    const int fragB = (quad * 64 + n16) * 8;    // + ni*128 shorts
    const int woff = w * 1024 + lane * 16;

    f32x4 zero = {0.f, 0.f, 0.f, 0.f};

    // ---- phase A: stats (stage B planes only: 8KB/chunk) ----
    float m0[4] = {-1e30f, -1e30f, -1e30f, -1e30f};
    float l0[4] = {0.f, 0.f, 0.f, 0.f};
    {   // prologue: chunk 0 -> buf 0
        char* d = (char*)sT[0];
        glds16(tBase + woff, d + w * 1024);
        glds16(tBase + woff + 4096, d + w * 1024 + 4096);
    }
    for (int jc = 0; jc < 32; ++jc) {
        __syncthreads();                        // drain DMA(cur), sync prev compute
        const int cur = jc & 1;
        if (jc + 1 < 32) {                      // prefetch next into other buf
            const char* g = tBase + (size_t)(jc + 1) * (TILE_SH * 2);
            char* d = (char*)sT[cur ^ 1];
            glds16(g + woff, d + w * 1024);
            glds16(g + woff + 4096, d + w * 1024 + 4096);
        }
        const unsigned short* t = sT[cur];
        f32x4 s[4];
        #pragma unroll
        for (int ni = 0; ni < 4; ++ni) {
            bf16x8 bhi = *reinterpret_cast<const bf16x8*>(t + fragB + ni * 128);
            bf16x8 blo = *reinterpret_cast<const bf16x8*>(t + 2048 + fragB + ni * 128);
            f32x4 acc = zero;
            acc = __builtin_amdgcn_mfma_f32_16x16x32_bf16(ahi, bhi, acc, 0, 0, 0);
            acc = __builtin_amdgcn_mfma_f32_16x16x32_bf16(ahi, blo, acc, 0, 0, 0);
            acc = __builtin_amdgcn_mfma_f32_16x16x32_bf16(alo, bhi, acc, 0, 0, 0);
            acc = __builtin_amdgcn_mfma_f32_16x16x32_bf16(alo, blo, acc, 0, 0, 0);
            s[ni] = acc;
        }
        #pragma unroll
        for (int r = 0; r < 4; ++r) {
            float v0 = s[0][r], v1 = s[1][r], v2 = s[2][r], v3 = s[3][r];
            float mx = fmaxf(fmaxf(v0, v1), fmaxf(v2, v3));
            float mn = fmaxf(m0[r], mx);
            l0[r] = l0[r] * __expf(m0[r] - mn)
                  + __expf(v0 - mn) + __expf(v1 - mn)
                  + __expf(v2 - mn) + __expf(v3 - mn);
            m0[r] = mn;
        }
    }
    // prologue for phase B: chunk 0 -> buf 0 (all waves passed barrier(jc=31),
    // so compute(30) on buf0 is complete block-wide; WAR safe)
    {
        char* d = (char*)sT[0];
        glds16(tBase + woff, d + w * 1024);
        glds16(tBase + woff + 4096, d + w * 1024 + 4096);
        glds16(tBase + woff + 8192, d + w * 1024 + 8192);
        glds16(tBase + woff + 12288, d + w * 1024 + 12288);
    }
    #pragma unroll
    for (int off = 1; off <= 8; off <<= 1) {        // butterfly: all 16 lanes
        #pragma unroll
        for (int r = 0; r < 4; ++r) {
            float m2 = __shfl_xor(m0[r], off, 64);
            float l2 = __shfl_xor(l0[r], off, 64);
            float mn = fmaxf(m0[r], m2);
            l0[r] = l0[r] * __expf(m0[r] - mn) + l2 * __expf(m2 - mn);
            m0[r] = mn;
        }
    }
    float mr[4], li[4];
    #pragma unroll
    for (int r = 0; r < 4; ++r) { mr[r] = m0[r]; li[r] = 1.f / l0[r]; }

    // ---- phase B: P + PV (full 16KB tiles) ----
    f32x4 o[4];
    #pragma unroll
    for (int di = 0; di < 4; ++di) o[di] = zero;

    for (int jc = 0; jc < 32; ++jc) {
        __syncthreads();                        // drain DMA(cur), sync prev compute
        const int cur = jc & 1;
        if (jc + 1 < 32) {                      // prefetch next into other buf
            const char* g = tBase + (size_t)(jc + 1) * (TILE_SH * 2);
            char* d = (char*)sT[cur ^ 1];
            glds16(g + woff, d + w * 1024);
            glds16(g + woff + 4096, d + w * 1024 + 4096);
            glds16(g + woff + 8192, d + w * 1024 + 8192);
            glds16(g + woff + 12288, d + w * 1024 + 12288);
        }
        const unsigned short* t = sT[cur];
        const int jb = jc * 64;
        #pragma unroll
        for (int ni = 0; ni < 4; ++ni) {
            bf16x8 bhi = *reinterpret_cast<const bf16x8*>(t + fragB + ni * 128);
            bf16x8 blo = *reinterpret_cast<const bf16x8*>(t + 2048 + fragB + ni * 128);
            f32x4 acc = zero;
            acc = __builtin_amdgcn_mfma_f32_16x16x32_bf16(ahi, bhi, acc, 0, 0, 0);
            acc = __builtin_amdgcn_mfma_f32_16x16x32_bf16(ahi, blo, acc, 0, 0, 0);
            acc = __builtin_amdgcn_mfma_f32_16x16x32_bf16(alo, bhi, acc, 0, 0, 0);
            acc = __builtin_amdgcn_mfma_f32_16x16x32_bf16(alo, blo, acc, 0, 0, 0);
            #pragma unroll
            for (int r = 0; r < 4; ++r) {
                float p = __expf(acc[r] - mr[r]) * li[r];
                const int sidx = (quad * 4 + r) * 68 + ni * 16 + n16;
                psf[sidx] = p;
                ps[sidx] = f2b(p);
            }
        }
        // vectorized NT store of fp32 P: 4 rows x 256B contiguous per instr
        #pragma unroll
        for (int rr = 0; rr < 4; ++rr) {
            const int prow = rr * 4 + quad;
            const int pcol = n16 * 4;
            f32x4 val = *reinterpret_cast<f32x4*>(psf + prow * 68 + pcol);
            __builtin_nontemporal_store(val,
                reinterpret_cast<f32x4*>(outP + (size_t)(hL + rbase + prow) * LN + jb + pcol));
        }
        // PV: O += P(chunk) @ V(chunk); in-wave LDS hazards ordered by lgkmcnt
        #pragma unroll
        for (int ks = 0; ks < 2; ++ks) {
            const bf16x8 pa = *reinterpret_cast<const bf16x8*>(ps + n16 * 68 + ks * 32 + quad * 8);
            #pragma unroll
            for (int di = 0; di < 4; ++di) {
                const bf16x8 vb = *reinterpret_cast<const bf16x8*>(
                    t + 4096 + ((ks * 4 + quad) * 64 + di * 16 + n16) * 8);
                o[di] = __builtin_amdgcn_mfma_f32_16x16x32_bf16(pa, vb, o[di], 0, 0, 0);
            }
        }
    }
    #pragma unroll
    for (int di = 0; di < 4; ++di) {
        #pragma unroll
        for (int r = 0; r < 4; ++r) {
            const int grow = rbase + quad * 4 + r;
            __builtin_nontemporal_store(o[di][r],
                &outO[(size_t)(hL + grow) * 64 + di * 16 + n16]);
        }
    }
}

// ---------------------------------------------------------------------------
extern "C" void kernel_launch(void* const* d_in, const int* in_sizes, int n_in,
                              void* d_out, int out_size, void* d_ws, size_t ws_size,
                              hipStream_t stream)
{
    (void)in_sizes; (void)n_in; (void)out_size; (void)ws_size;
    const float* q  = (const float*)d_in[0];
    const float* v  = (const float*)d_in[1];
    const float* Wa = (const float*)d_in[2];
    const float* ba = (const float*)d_in[3];
    const float* Wb = (const float*)d_in[4];
    const float* bb = (const float*)d_in[5];

    float* out = (float*)d_out;
    char* wsb = (char*)d_ws;
    const size_t CBb = (size_t)HN * LN * KR * 2;   // 2MB per bf16 plane
    unsigned short* Chi  = (unsigned short*)(wsb + 0 * CBb);
    unsigned short* Clo  = (unsigned short*)(wsb + 1 * CBb);
    unsigned short* Tile = (unsigned short*)(wsb + 2 * CBb);   // 16 KB x 512 = 8MB

    float* outO = out;                          // [H*L*64]
    float* outP = out + (size_t)HN * LN * 64;   // [H*L*L]

    hipLaunchKernelGGL(k_cb, dim3(512), dim3(256), 0, stream,
                       q, Wa, ba, Wb, bb, Chi, Clo, Tile);
    hipLaunchKernelGGL(k_vtc, dim3(512), dim3(256), 0, stream, v, Tile);
    hipLaunchKernelGGL(k_pvs, dim3(512), dim3(256), 0, stream,
                       Chi, Clo, Tile, outO, outP);
}